// Round 11
// baseline (246.149 us; speedup 1.0000x reference)
//
#include <hip/hip_runtime.h>

typedef unsigned short u16;
typedef unsigned int u32;
typedef __attribute__((ext_vector_type(8))) short short8;
typedef __attribute__((ext_vector_type(4))) float f32x4;

#define BB 8
#define CCH 256
#define HH 64
#define WW 64
#define HP 66
#define NPOS 4096
#define KTOT 2304

// ---- ws layout (bytes) ----
#define XT_BYTES   17842176ull                 // bf16 [8][66][66][256]
#define W2R_OFF    17842176ull                 // bf16 [256][2304]
#define WOFF2_OFF  19021824ull                 // bf16 [32][2304]
#define P_OFF      19169280ull                 // fp32 [8][9][18][4096] partials
#define GOFF_OFF   40402944ull                 // int4 [8][9][4096] corner offsets
#define GW_OFF     45121536ull                 // float4 [8][9][4096] bilinear weights
#define WS_NEED    49840128ull

__device__ __forceinline__ float bf2f(u16 u) {
    union { u32 u; float f; } v; v.u = ((u32)u) << 16; return v.f;
}
__device__ __forceinline__ u16 f2bf(float f) {
    union { float f; u32 u; } v; v.f = f;
    u32 r = v.u + 0x7FFFu + ((v.u >> 16) & 1u);
    return (u16)(r >> 16);
}
__device__ __forceinline__ u32 pk2(float a, float b) {
    return (u32)f2bf(a) | ((u32)f2bf(b) << 16);
}
__device__ __forceinline__ void bf2x2(u32 p, float& a, float& b) {
    union { u32 u; float f; } va, vb;
    va.u = p << 16; vb.u = p & 0xffff0000u;
    a = va.f; b = vb.f;
}
// async global->LDS, 16B per lane; LDS dest = wave-uniform base + lane*16
__device__ __forceinline__ void ldg_lds16(const u16* g, u16* l) {
    __builtin_amdgcn_global_load_lds((const __attribute__((address_space(1))) u32*)g,
                                     (__attribute__((address_space(3))) u32*)l, 16, 0, 0);
}

// ---- K0: reorder weights via LDS transpose: W2r[o][k*256+c] = w[o][c][k] ----
__global__ __launch_bounds__(256) void k_prep(const float* __restrict__ w, const float* __restrict__ w_off,
                                              u16* __restrict__ W2r, u16* __restrict__ Woff2) {
    __shared__ float L[2304];
    int t = threadIdx.x;
    if (blockIdx.x < 256) {
        int o = blockIdx.x;
        const float* src = w + (size_t)o * 2304;
#pragma unroll
        for (int j = 0; j < 9; ++j) L[j * 256 + t] = src[j * 256 + t];
        __syncthreads();
        u16* dst = W2r + (size_t)o * 2304;
#pragma unroll
        for (int k = 0; k < 9; ++k) dst[k * 256 + t] = f2bf(L[t * 9 + k]);   // stride-9: conflict-free
    } else {
        for (int o2 = 0; o2 < 32; ++o2) {
            if (o2 < 18) {
                const float* src = w_off + (size_t)o2 * 2304;
#pragma unroll
                for (int j = 0; j < 9; ++j) L[j * 256 + t] = src[j * 256 + t];
                __syncthreads();
#pragma unroll
                for (int k = 0; k < 9; ++k) Woff2[(size_t)o2 * 2304 + k * 256 + t] = f2bf(L[t * 9 + k]);
                __syncthreads();
            } else {
#pragma unroll
                for (int k = 0; k < 9; ++k) Woff2[(size_t)o2 * 2304 + k * 256 + t] = 0;
            }
        }
    }
}

// ---- K0b: zero the 1-px padding border of xT (replaces full memset) ----
__global__ void k_border(u16* __restrict__ xT) {
    int b = blockIdx.x, m = blockIdx.y;
    int y, x;
    if (m < 66)       { y = 0;  x = m; }
    else if (m < 132) { y = 65; x = m - 66; }
    else if (m < 196) { y = m - 132 + 1; x = 0; }
    else              { y = m - 196 + 1; x = 65; }
    u16* p = xT + ((size_t)(b * HP + y) * HP + x) * CCH + threadIdx.x * 4;
    uint2 zz; zz.x = 0; zz.y = 0;
    *(uint2*)p = zz;
}

// ---- K1: transpose+pad fp32 NCHW -> bf16 NHWC padded; x = batch (XCD-pinned) ----
__global__ __launch_bounds__(256) void k_transpose(const float* __restrict__ x, u16* __restrict__ xT) {
    __shared__ __align__(16) float T[64][72];
    int b = blockIdx.x, y = blockIdx.y, c0 = blockIdx.z * 64;
    int t = threadIdx.x;
    {
        int i = t >> 2, seg = t & 3;   // channel i, 16-float x-segment
        const float* src = x + (((size_t)(b * CCH + c0 + i) * HH + y) * WW) + seg * 16;
        float4 v0 = *(const float4*)(src);
        float4 v1 = *(const float4*)(src + 4);
        float4 v2 = *(const float4*)(src + 8);
        float4 v3 = *(const float4*)(src + 12);
        *(float4*)&T[i][seg * 16]      = v0;
        *(float4*)&T[i][seg * 16 + 4]  = v1;
        *(float4*)&T[i][seg * 16 + 8]  = v2;
        *(float4*)&T[i][seg * 16 + 12] = v3;
    }
    __syncthreads();
    {
        int xc = t >> 2, cs = t & 3;   // x-position xc, 16-channel segment cs
        u16* dst = xT + (((size_t)(b * HP + y + 1) * HP) + (xc + 1)) * CCH + c0 + cs * 16;
        u32 p[8];
#pragma unroll
        for (int j = 0; j < 8; ++j)
            p[j] = pk2(T[cs * 16 + 2 * j][xc], T[cs * 16 + 2 * j + 1][xc]);
        uint4 d0, d1;
        d0.x = p[0]; d0.y = p[1]; d0.z = p[2]; d0.w = p[3];
        d1.x = p[4]; d1.y = p[5]; d1.z = p[6]; d1.w = p[7];
        *(uint4*)dst = d0;
        *(uint4*)(dst + 8) = d1;
    }
}

// ---- K2: offset conv GEMM, K-split by tap; coalesced swizzled staging, BK=64 (R10-verified) ----
__global__ __launch_bounds__(256) void k_offconv(const u16* __restrict__ xT,
                                                 const u16* __restrict__ Woff2,
                                                 float* __restrict__ P) {
    __shared__ __align__(16) u16 AS[2][2048];
    __shared__ __align__(16) u16 BS[2][8192];
    int b = blockIdx.x, k9 = blockIdx.y;
    int pos0 = blockIdx.z * 128;
    int ky = k9 / 3, kx = k9 % 3;
    int t = threadIdx.x, lane = t & 63, wv = t >> 6;

    int srow = lane >> 3;
    int sw8 = ((lane & 7) ^ srow) << 3;
    const u16* pA = Woff2 + (size_t)k9 * 256;
    const u16* pXb = xT + (size_t)b * HP * HP * CCH;

    f32x4 acc[2][2];
    f32x4 z = {0.f, 0.f, 0.f, 0.f};
    acc[0][0] = z; acc[0][1] = z; acc[1][0] = z; acc[1][1] = z;

    auto stage = [&](int cs, int d) {
        int koff = cs * 64;
        {
            int row = wv * 8 + srow;
            ldg_lds16(pA + (size_t)row * KTOT + koff + sw8, &AS[d][wv * 512]);
        }
#pragma unroll
        for (int i = 0; i < 4; ++i) {
            int inst = wv * 4 + i;
            int rowg = pos0 + inst * 8 + srow;
            int py_ = rowg >> 6, px_ = rowg & 63;
            const u16* g = pXb + (((size_t)(py_ + ky) * HP) + px_ + kx) * CCH + koff + sw8;
            ldg_lds16(g, &BS[d][inst * 512]);
        }
    };

    stage(0, 0);
    __syncthreads();

    int buf = 0;
    int m = lane & 15, q = lane >> 4, key = lane & 7;
    for (int cs = 0; cs < 4; ++cs) {
        if (cs < 3) stage(cs + 1, buf ^ 1);
#pragma unroll
        for (int j = 0; j < 2; ++j) {
            int slot8 = (((j * 4 + q) ^ key) << 3);
            short8 a0 = *(const short8*)&AS[buf][m * 64 + slot8];
            short8 a1 = *(const short8*)&AS[buf][(16 + m) * 64 + slot8];
            short8 b0 = *(const short8*)&BS[buf][(wv * 32 + m) * 64 + slot8];
            short8 b1 = *(const short8*)&BS[buf][(wv * 32 + 16 + m) * 64 + slot8];
            acc[0][0] = __builtin_amdgcn_mfma_f32_16x16x32_bf16(a0, b0, acc[0][0], 0, 0, 0);
            acc[0][1] = __builtin_amdgcn_mfma_f32_16x16x32_bf16(a0, b1, acc[0][1], 0, 0, 0);
            acc[1][0] = __builtin_amdgcn_mfma_f32_16x16x32_bf16(a1, b0, acc[1][0], 0, 0, 0);
            acc[1][1] = __builtin_amdgcn_mfma_f32_16x16x32_bf16(a1, b1, acc[1][1], 0, 0, 0);
        }
        __syncthreads();
        buf ^= 1;
    }
    int nn = lane & 15;
    float* Pp = P + (size_t)(b * 9 + k9) * 18 * NPOS;
#pragma unroll
    for (int ao = 0; ao < 2; ++ao)
#pragma unroll
        for (int bn = 0; bn < 2; ++bn) {
            int pos = pos0 + wv * 32 + bn * 16 + nn;
#pragma unroll
            for (int r = 0; r < 4; ++r) {
                int o = ao * 16 + q * 4 + r;
                if (o < 18) Pp[o * NPOS + pos] = acc[ao][bn][r];
            }
        }
}

// ---- K2b: reduce 9 tap-partials + bias -> per-(b,tap,pos) corner offsets + bilinear weights ----
__global__ __launch_bounds__(256) void k_reduce(const float* __restrict__ P,
                                                const float* __restrict__ b_off,
                                                int4* __restrict__ G_off,
                                                float4* __restrict__ G_w) {
    int b = blockIdx.x;
    int pos = blockIdx.y * 256 + threadIdx.x;
    float s[18];
#pragma unroll
    for (int o = 0; o < 18; ++o) s[o] = b_off[o];
    const float* Pp = P + (size_t)(b * 9) * 18 * NPOS + pos;
    for (int k9 = 0; k9 < 9; ++k9) {
#pragma unroll
        for (int o = 0; o < 18; ++o)
            s[o] += Pp[(k9 * 18 + o) * NPOS];
    }
    int y = pos >> 6, x = pos & 63;
    int base = b * HP * HP;
#pragma unroll
    for (int op = 0; op < 9; ++op) {
        float pyf = (float)(y - 1 + op / 3) + s[2 * op];
        float pxf = (float)(x - 1 + op % 3) + s[2 * op + 1];
        float y0f = floorf(pyf), x0f = floorf(pxf);
        int y0 = (int)y0f, x0 = (int)x0f;
        int y1 = y0 + 1, x1 = x0 + 1;
        float wy1 = pyf - y0f, wy0 = 1.f - wy1;
        float wx1 = pxf - x0f, wx0 = 1.f - wx1;
        bool vy0 = (y0 >= 0) & (y0 < HH), vy1 = (y1 >= 0) & (y1 < HH);
        bool vx0 = (x0 >= 0) & (x0 < WW), vx1 = (x1 >= 0) & (x1 < WW);
        int yc0 = min(max(y0, 0), HH - 1), yc1 = min(max(y1, 0), HH - 1);
        int xc0 = min(max(x0, 0), WW - 1), xc1 = min(max(x1, 0), WW - 1);
        int4 go;
        go.x = (base + (yc0 + 1) * HP + (xc0 + 1)) * CCH;
        go.y = (base + (yc0 + 1) * HP + (xc1 + 1)) * CCH;
        go.z = (base + (yc1 + 1) * HP + (xc0 + 1)) * CCH;
        go.w = (base + (yc1 + 1) * HP + (xc1 + 1)) * CCH;
        float4 gw;
        gw.x = (vy0 & vx0) ? wy0 * wx0 : 0.f;
        gw.y = (vy0 & vx1) ? wy0 * wx1 : 0.f;
        gw.z = (vy1 & vx0) ? wy1 * wx0 : 0.f;
        gw.w = (vy1 & vx1) ? wy1 * wx1 : 0.f;
        size_t gi = (((size_t)(b * 9 + op)) << 12) + pos;
        G_off[gi] = go;
        G_w[gi] = gw;
    }
}

// ---- K4: FUSED deformable GEMM 128x128, BK=64, dbuf. B-tile = 4-corner bilinear gather
//      (8-lane groups read 16B/lane contiguous from L2-resident xT) blended in registers,
//      ds_write_b128 into the R7-verified swizzled LDS layout. A staged via global_load_lds. ----
__global__ __launch_bounds__(256) void k_gemm(const u16* __restrict__ xT,
                                              const u16* __restrict__ W2r,
                                              const int4* __restrict__ G_off,
                                              const float4* __restrict__ G_w,
                                              const float* __restrict__ bias,
                                              float* __restrict__ out) {
    __shared__ __align__(16) u16 AS[2][8192];   // [128 row][64 k], swizzled chunks, 16KB
    __shared__ __align__(16) u16 BS[2][8192];
    int b = blockIdx.x;
    int o0 = blockIdx.y * 128;
    int pos0 = blockIdx.z * 128;
    int t = threadIdx.x, lane = t & 63, wv = t >> 6;
    int wr = wv >> 1, wc = wv & 1;

    // A staging (R7 pattern): instr covers 8 rows x 128B
    int srow = lane >> 3;
    int sw8 = ((lane & 7) ^ srow) << 3;
    const u16* pA = W2r + (size_t)o0 * KTOT;

    // B gather geometry: thread -> row rB (32 rows/round), 8-ch chunk cB; swizzled LDS slot
    int rB = t >> 3;                 // 0..31
    int cB = (t & 7) * 8;            // channel chunk within 64-ch window
    int slotB = ((t & 7) ^ (rB & 7)) << 3;
    int gb9 = b * 9;

    f32x4 acc[4][4];
    f32x4 z = {0.f, 0.f, 0.f, 0.f};
#pragma unroll
    for (int i = 0; i < 4; ++i)
#pragma unroll
        for (int j = 0; j < 4; ++j) acc[i][j] = z;

    auto stageA = [&](int s, int d) {
        int koff = (s >> 2) * 256 + (s & 3) * 64;
#pragma unroll
        for (int i = 0; i < 4; ++i) {
            int inst = wv * 4 + i;
            int row = inst * 8 + srow;
            ldg_lds16(pA + (size_t)row * KTOT + koff + sw8, &AS[d][inst * 512]);
        }
    };

    uint4 crn[4][4];
    float4 gwr[4];
    auto gatherB = [&](int s) {
        int k9 = s >> 2, c0 = (s & 3) * 64;
#pragma unroll
        for (int r = 0; r < 4; ++r) {
            size_t gi = (((size_t)(gb9 + k9)) << 12) + pos0 + r * 32 + rB;
            int4 go = G_off[gi];
            gwr[r] = G_w[gi];
            int cc = c0 + cB;
            crn[r][0] = *(const uint4*)(xT + go.x + cc);
            crn[r][1] = *(const uint4*)(xT + go.y + cc);
            crn[r][2] = *(const uint4*)(xT + go.z + cc);
            crn[r][3] = *(const uint4*)(xT + go.w + cc);
        }
    };
    auto blendB = [&](int d) {
#pragma unroll
        for (int r = 0; r < 4; ++r) {
            float w0 = gwr[r].x, w1 = gwr[r].y, w2 = gwr[r].z, w3 = gwr[r].w;
            float v[8];
#pragma unroll
            for (int dw = 0; dw < 4; ++dw) {
                u32 p0 = ((const u32*)&crn[r][0])[dw];
                u32 p1 = ((const u32*)&crn[r][1])[dw];
                u32 p2 = ((const u32*)&crn[r][2])[dw];
                u32 p3 = ((const u32*)&crn[r][3])[dw];
                float a0, b0_, a1, b1_, a2, b2_, a3, b3_;
                bf2x2(p0, a0, b0_);
                bf2x2(p1, a1, b1_);
                bf2x2(p2, a2, b2_);
                bf2x2(p3, a3, b3_);
                v[2 * dw]     = w0 * a0 + w1 * a1 + w2 * a2 + w3 * a3;
                v[2 * dw + 1] = w0 * b0_ + w1 * b1_ + w2 * b2_ + w3 * b3_;
            }
            uint4 pkd;
            pkd.x = pk2(v[0], v[1]); pkd.y = pk2(v[2], v[3]);
            pkd.z = pk2(v[4], v[5]); pkd.w = pk2(v[6], v[7]);
            *(uint4*)&BS[d][(r * 32 + rB) * 64 + slotB] = pkd;
        }
    };

    // prologue: step 0
    gatherB(0);
    stageA(0, 0);
    blendB(0);
    __syncthreads();

    int buf = 0;
    int m = lane & 15, q = lane >> 4, key = lane & 7;
    for (int step = 0; step < 36; ++step) {
        if (step < 35) {
            gatherB(step + 1);          // global loads in flight during MFMA below
            stageA(step + 1, buf ^ 1);
        }
#pragma unroll
        for (int j = 0; j < 2; ++j) {
            int slot8 = (((j * 4 + q) ^ key) << 3);
            short8 af[4], bfr[4];
#pragma unroll
            for (int ao = 0; ao < 4; ++ao)
                af[ao] = *(const short8*)&AS[buf][(wr * 64 + ao * 16 + m) * 64 + slot8];
#pragma unroll
            for (int bn = 0; bn < 4; ++bn)
                bfr[bn] = *(const short8*)&BS[buf][(wc * 64 + bn * 16 + m) * 64 + slot8];
#pragma unroll
            for (int ao = 0; ao < 4; ++ao)
#pragma unroll
                for (int bn = 0; bn < 4; ++bn)
                    acc[ao][bn] = __builtin_amdgcn_mfma_f32_16x16x32_bf16(af[ao], bfr[bn], acc[ao][bn], 0, 0, 0);
        }
        if (step < 35) blendB(buf ^ 1);
        __syncthreads();
        buf ^= 1;
    }

    // epilogue: bias + sigmoid -> fp32 NCHW
    int nn = lane & 15;
#pragma unroll
    for (int ao = 0; ao < 4; ++ao) {
        int ob = o0 + wr * 64 + ao * 16 + q * 4;
#pragma unroll
        for (int bn = 0; bn < 4; ++bn) {
            int pos = pos0 + wc * 64 + bn * 16 + nn;
#pragma unroll
            for (int r = 0; r < 4; ++r) {
                float v = acc[ao][bn][r] + bias[ob + r];
                float sg = 1.0f / (1.0f + __expf(-v));
                out[(size_t)((b * CCH + ob + r) * NPOS) + pos] = sg;
            }
        }
    }
}

extern "C" void kernel_launch(void* const* d_in, const int* in_sizes, int n_in,
                              void* d_out, int out_size, void* d_ws, size_t ws_size,
                              hipStream_t stream) {
    const float* x     = (const float*)d_in[0];
    const float* w_off = (const float*)d_in[1];
    const float* b_off = (const float*)d_in[2];
    const float* w     = (const float*)d_in[3];
    const float* bias  = (const float*)d_in[4];
    float* out = (float*)d_out;

    char* ws = (char*)d_ws;
    u16*    xT    = (u16*)ws;
    u16*    W2r   = (u16*)(ws + W2R_OFF);
    u16*    Woff2 = (u16*)(ws + WOFF2_OFF);
    float*  P     = (float*)(ws + P_OFF);
    int4*   G_off = (int4*)(ws + GOFF_OFF);
    float4* G_w   = (float4*)(ws + GW_OFF);

    if (ws_size < WS_NEED) return;

    k_prep<<<257, 256, 0, stream>>>(w, w_off, W2r, Woff2);
    k_border<<<dim3(8, 260), 64, 0, stream>>>(xT);
    k_transpose<<<dim3(8, 64, 4), 256, 0, stream>>>(x, xT);
    k_offconv<<<dim3(8, 9, 32), 256, 0, stream>>>(xT, Woff2, P);
    k_reduce<<<dim3(8, 16), 256, 0, stream>>>(P, b_off, G_off, G_w);
    k_gemm<<<dim3(8, 2, 32), 256, 0, stream>>>(xT, W2r, G_off, G_w, bias, out);
}

// Round 12
// 213.814 us; speedup vs baseline: 1.1512x; 1.1512x over previous
//
#include <hip/hip_runtime.h>

typedef unsigned short u16;
typedef unsigned int u32;
typedef __attribute__((ext_vector_type(8))) short short8;
typedef __attribute__((ext_vector_type(4))) float f32x4;

#define BB 8
#define CCH 256
#define HH 64
#define WW 64
#define HP 66
#define NPOS 4096
#define KTOT 2304

// ---- ws layout (bytes) ----
#define XT_BYTES   17842176ull                 // bf16 [8][66][66][256]
#define W2R_OFF    17842176ull                 // bf16 [256][2304]
#define WOFF2_OFF  19021824ull                 // bf16 [32][2304]
#define P_OFF      19169280ull                 // fp32 [8][9][18][4096] partials
#define OFF2_OFF   40402944ull                 // float2 [8][9][4096]
#define S_OFF      42762240ull                 // bf16 [nb][9][4096][256]
#define S_BATCH    18874368ull                 // bytes per batch

__device__ __forceinline__ float bf2f(u16 u) {
    union { u32 u; float f; } v; v.u = ((u32)u) << 16; return v.f;
}
__device__ __forceinline__ u16 f2bf(float f) {
    union { float f; u32 u; } v; v.f = f;
    u32 r = v.u + 0x7FFFu + ((v.u >> 16) & 1u);
    return (u16)(r >> 16);
}
__device__ __forceinline__ u32 pk2(float a, float b) {
    return (u32)f2bf(a) | ((u32)f2bf(b) << 16);
}
__device__ __forceinline__ void bf2x2(u32 p, float& a, float& b) {
    union { u32 u; float f; } va, vb;
    va.u = p << 16; vb.u = p & 0xffff0000u;
    a = va.f; b = vb.f;
}
// async global->LDS, 16B per lane; LDS dest = wave-uniform base + lane*16
__device__ __forceinline__ void ldg_lds16(const u16* g, u16* l) {
    __builtin_amdgcn_global_load_lds((const __attribute__((address_space(1))) u32*)g,
                                     (__attribute__((address_space(3))) u32*)l, 16, 0, 0);
}

// ---- K_PRE: fused weight-reorder + border-zero + transpose (independent work, 1 launch) ----
// blocks [0,257): weight reorder; [257,777): border zero; [777,2825): NCHW->NHWC transpose
__global__ __launch_bounds__(256) void k_pre(const float* __restrict__ w, const float* __restrict__ w_off,
                                             const float* __restrict__ x,
                                             u16* __restrict__ W2r, u16* __restrict__ Woff2,
                                             u16* __restrict__ xT) {
    __shared__ __align__(16) float SH[4608];   // prep uses 2304; transpose uses 64x72
    int bx = blockIdx.x;
    int t = threadIdx.x;
    if (bx < 256) {
        int o = bx;
        const float* src = w + (size_t)o * 2304;
#pragma unroll
        for (int j = 0; j < 9; ++j) SH[j * 256 + t] = src[j * 256 + t];
        __syncthreads();
        u16* dst = W2r + (size_t)o * 2304;
#pragma unroll
        for (int k = 0; k < 9; ++k) dst[k * 256 + t] = f2bf(SH[t * 9 + k]);   // stride-9: conflict-free
    } else if (bx == 256) {
        for (int o2 = 0; o2 < 32; ++o2) {
            if (o2 < 18) {
                const float* src = w_off + (size_t)o2 * 2304;
#pragma unroll
                for (int j = 0; j < 9; ++j) SH[j * 256 + t] = src[j * 256 + t];
                __syncthreads();
#pragma unroll
                for (int k = 0; k < 9; ++k) Woff2[(size_t)o2 * 2304 + k * 256 + t] = f2bf(SH[t * 9 + k]);
                __syncthreads();
            } else {
#pragma unroll
                for (int k = 0; k < 9; ++k) Woff2[(size_t)o2 * 2304 + k * 256 + t] = 0;
            }
        }
    } else if (bx < 777) {
        // border zero: 2080 positions, 4 per block (64 lanes each)
        int idx = (bx - 257) * 4 + (t >> 6);
        int b = idx / 260, m = idx - b * 260;
        int y, xx;
        if (m < 66)       { y = 0;  xx = m; }
        else if (m < 132) { y = 65; xx = m - 66; }
        else if (m < 196) { y = m - 132 + 1; xx = 0; }
        else              { y = m - 196 + 1; xx = 65; }
        u16* p = xT + ((size_t)(b * HP + y) * HP + xx) * CCH + (t & 63) * 4;
        uint2 zz; zz.x = 0; zz.y = 0;
        *(uint2*)p = zz;
    } else {
        int idx = bx - 777;               // 2048 transpose tiles
        int b = idx & 7;                  // XCD pin
        int r = idx >> 3;
        int y = r & 63, c0 = (r >> 6) * 64;
        {
            int i = t >> 2, seg = t & 3;   // channel i, 16-float x-segment
            const float* src = x + (((size_t)(b * CCH + c0 + i) * HH + y) * WW) + seg * 16;
            float4 v0 = *(const float4*)(src);
            float4 v1 = *(const float4*)(src + 4);
            float4 v2 = *(const float4*)(src + 8);
            float4 v3 = *(const float4*)(src + 12);
            *(float4*)&SH[i * 72 + seg * 16]      = v0;
            *(float4*)&SH[i * 72 + seg * 16 + 4]  = v1;
            *(float4*)&SH[i * 72 + seg * 16 + 8]  = v2;
            *(float4*)&SH[i * 72 + seg * 16 + 12] = v3;
        }
        __syncthreads();
        {
            int xc = t >> 2, cs = t & 3;   // x-position xc, 16-channel segment cs
            u16* dst = xT + (((size_t)(b * HP + y + 1) * HP) + (xc + 1)) * CCH + c0 + cs * 16;
            u32 p[8];
#pragma unroll
            for (int j = 0; j < 8; ++j)
                p[j] = pk2(SH[(cs * 16 + 2 * j) * 72 + xc], SH[(cs * 16 + 2 * j + 1) * 72 + xc]);
            uint4 d0, d1;
            d0.x = p[0]; d0.y = p[1]; d0.z = p[2]; d0.w = p[3];
            d1.x = p[4]; d1.y = p[5]; d1.z = p[6]; d1.w = p[7];
            *(uint4*)dst = d0;
            *(uint4*)(dst + 8) = d1;
        }
    }
}

// ---- K2: offset conv GEMM, K-split by tap; coalesced swizzled staging, BK=64 (R10-verified) ----
__global__ __launch_bounds__(256) void k_offconv(const u16* __restrict__ xT,
                                                 const u16* __restrict__ Woff2,
                                                 float* __restrict__ P) {
    __shared__ __align__(16) u16 AS[2][2048];
    __shared__ __align__(16) u16 BS[2][8192];
    int b = blockIdx.x, k9 = blockIdx.y;
    int pos0 = blockIdx.z * 128;
    int ky = k9 / 3, kx = k9 % 3;
    int t = threadIdx.x, lane = t & 63, wv = t >> 6;

    int srow = lane >> 3;
    int sw8 = ((lane & 7) ^ srow) << 3;
    const u16* pA = Woff2 + (size_t)k9 * 256;
    const u16* pXb = xT + (size_t)b * HP * HP * CCH;

    f32x4 acc[2][2];
    f32x4 z = {0.f, 0.f, 0.f, 0.f};
    acc[0][0] = z; acc[0][1] = z; acc[1][0] = z; acc[1][1] = z;

    auto stage = [&](int cs, int d) {
        int koff = cs * 64;
        {
            int row = wv * 8 + srow;
            ldg_lds16(pA + (size_t)row * KTOT + koff + sw8, &AS[d][wv * 512]);
        }
#pragma unroll
        for (int i = 0; i < 4; ++i) {
            int inst = wv * 4 + i;
            int rowg = pos0 + inst * 8 + srow;
            int py_ = rowg >> 6, px_ = rowg & 63;
            const u16* g = pXb + (((size_t)(py_ + ky) * HP) + px_ + kx) * CCH + koff + sw8;
            ldg_lds16(g, &BS[d][inst * 512]);
        }
    };

    stage(0, 0);
    __syncthreads();

    int buf = 0;
    int m = lane & 15, q = lane >> 4, key = lane & 7;
    for (int cs = 0; cs < 4; ++cs) {
        if (cs < 3) stage(cs + 1, buf ^ 1);
#pragma unroll
        for (int j = 0; j < 2; ++j) {
            int slot8 = (((j * 4 + q) ^ key) << 3);
            short8 a0 = *(const short8*)&AS[buf][m * 64 + slot8];
            short8 a1 = *(const short8*)&AS[buf][(16 + m) * 64 + slot8];
            short8 b0 = *(const short8*)&BS[buf][(wv * 32 + m) * 64 + slot8];
            short8 b1 = *(const short8*)&BS[buf][(wv * 32 + 16 + m) * 64 + slot8];
            acc[0][0] = __builtin_amdgcn_mfma_f32_16x16x32_bf16(a0, b0, acc[0][0], 0, 0, 0);
            acc[0][1] = __builtin_amdgcn_mfma_f32_16x16x32_bf16(a0, b1, acc[0][1], 0, 0, 0);
            acc[1][0] = __builtin_amdgcn_mfma_f32_16x16x32_bf16(a1, b0, acc[1][0], 0, 0, 0);
            acc[1][1] = __builtin_amdgcn_mfma_f32_16x16x32_bf16(a1, b1, acc[1][1], 0, 0, 0);
        }
        __syncthreads();
        buf ^= 1;
    }
    int nn = lane & 15;
    float* Pp = P + (size_t)(b * 9 + k9) * 18 * NPOS;
#pragma unroll
    for (int ao = 0; ao < 2; ++ao)
#pragma unroll
        for (int bn = 0; bn < 2; ++bn) {
            int pos = pos0 + wv * 32 + bn * 16 + nn;
#pragma unroll
            for (int r = 0; r < 4; ++r) {
                int o = ao * 16 + q * 4 + r;
                if (o < 18) Pp[o * NPOS + pos] = acc[ao][bn][r];
            }
        }
}

// ---- K2b: reduce 9 tap-partials + bias -> off2[b][tap][pos] = (dy,dx) ----
__global__ __launch_bounds__(256) void k_reduce(const float* __restrict__ P,
                                                const float* __restrict__ b_off,
                                                float2* __restrict__ off2) {
    int b = blockIdx.x;
    int pos = blockIdx.y * 256 + threadIdx.x;
    float s[18];
#pragma unroll
    for (int o = 0; o < 18; ++o) s[o] = b_off[o];
    const float* Pp = P + (size_t)(b * 9) * 18 * NPOS + pos;
    for (int k9 = 0; k9 < 9; ++k9) {
#pragma unroll
        for (int o = 0; o < 18; ++o)
            s[o] += Pp[(k9 * 18 + o) * NPOS];
    }
#pragma unroll
    for (int op = 0; op < 9; ++op) {
        float2 v; v.x = s[2 * op]; v.y = s[2 * op + 1];
        off2[(((size_t)(b * 9 + op)) << 12) + pos] = v;
    }
}

// ---- K3: materialize S[bl][k9][pos][c] bf16; 16-lane groups, uint4 (16B/lane) loads+stores ----
__global__ __launch_bounds__(256) void k_sample(const u16* __restrict__ xT,
                                                const float2* __restrict__ off2,
                                                u16* __restrict__ S, int b0) {
    int bl = blockIdx.x, b = b0 + bl, k9 = blockIdx.y;
    int pos0 = blockIdx.z * 64;
    int t = threadIdx.x, g = t >> 4, ll = t & 15;
    int ky = k9 / 3, kx = k9 % 3;
    int bbase = b * HP * HP;

    for (int i = 0; i < 4; ++i) {
        int pos = pos0 + g + i * 16;
        int y = pos >> 6, x = pos & 63;
        float2 off = off2[(((size_t)(b * 9 + k9)) << 12) + pos];
        float pyf = (float)(y - 1 + ky) + off.x;
        float pxf = (float)(x - 1 + kx) + off.y;
        float y0f = floorf(pyf), x0f = floorf(pxf);
        int y0 = (int)y0f, x0 = (int)x0f;
        int y1 = y0 + 1, x1 = x0 + 1;
        float wy1 = pyf - y0f, wy0 = 1.f - wy1;
        float wx1 = pxf - x0f, wx0 = 1.f - wx1;
        bool vy0 = (y0 >= 0) & (y0 < HH), vy1 = (y1 >= 0) & (y1 < HH);
        bool vx0 = (x0 >= 0) & (x0 < WW), vx1 = (x1 >= 0) & (x1 < WW);
        int yc0 = min(max(y0, 0), HH - 1), yc1 = min(max(y1, 0), HH - 1);
        int xc0 = min(max(x0, 0), WW - 1), xc1 = min(max(x1, 0), WW - 1);
        float w0 = (vy0 & vx0) ? wy0 * wx0 : 0.f;
        float w1 = (vy0 & vx1) ? wy0 * wx1 : 0.f;
        float w2 = (vy1 & vx0) ? wy1 * wx0 : 0.f;
        float w3 = (vy1 & vx1) ? wy1 * wx1 : 0.f;
        const u16* g0 = xT + (size_t)((bbase + (yc0 + 1) * HP + xc0 + 1)) * CCH;
        const u16* g1 = xT + (size_t)((bbase + (yc0 + 1) * HP + xc1 + 1)) * CCH;
        const u16* g2 = xT + (size_t)((bbase + (yc1 + 1) * HP + xc0 + 1)) * CCH;
        const u16* g3 = xT + (size_t)((bbase + (yc1 + 1) * HP + xc1 + 1)) * CCH;
        u16* sp = S + ((((size_t)(bl * 9 + k9)) << 12) + pos) * CCH;
#pragma unroll
        for (int cp = 0; cp < 2; ++cp) {
            int c = cp * 128 + ll * 8;   // 8 bf16 = 16B per lane; 16 lanes cover 128ch contiguous
            uint4 r0 = *(const uint4*)(g0 + c);
            uint4 r1 = *(const uint4*)(g1 + c);
            uint4 r2 = *(const uint4*)(g2 + c);
            uint4 r3 = *(const uint4*)(g3 + c);
            float v[8];
#pragma unroll
            for (int dw = 0; dw < 4; ++dw) {
                u32 p0 = ((const u32*)&r0)[dw];
                u32 p1 = ((const u32*)&r1)[dw];
                u32 p2 = ((const u32*)&r2)[dw];
                u32 p3 = ((const u32*)&r3)[dw];
                float a0, b0_, a1, b1_, a2, b2_, a3, b3_;
                bf2x2(p0, a0, b0_);
                bf2x2(p1, a1, b1_);
                bf2x2(p2, a2, b2_);
                bf2x2(p3, a3, b3_);
                v[2 * dw]     = w0 * a0 + w1 * a1 + w2 * a2 + w3 * a3;
                v[2 * dw + 1] = w0 * b0_ + w1 * b1_ + w2 * b2_ + w3 * b3_;
            }
            uint4 sv;
            sv.x = pk2(v[0], v[1]); sv.y = pk2(v[2], v[3]);
            sv.z = pk2(v[4], v[5]); sv.w = pk2(v[6], v[7]);
            *(uint4*)(sp + c) = sv;
        }
    }
}

// ---- K4: GEMM 128x128, BK=64, dbuf; row-major LDS + XOR-swizzled chunks (R10-verified) ----
__global__ __launch_bounds__(256) void k_gemm(const u16* __restrict__ S,
                                              const u16* __restrict__ W2r,
                                              const float* __restrict__ bias,
                                              float* __restrict__ out, int b0) {
    __shared__ __align__(16) u16 AS[2][8192];   // [128 row][64 k] row-major, swizzled chunks, 16KB
    __shared__ __align__(16) u16 BS[2][8192];
    int bl = blockIdx.x, b = b0 + bl;
    int o0 = blockIdx.y * 128;
    int pos0 = blockIdx.z * 128;
    int t = threadIdx.x, lane = t & 63, wv = t >> 6;
    int wr = wv >> 1, wc = wv & 1;

    int srow = lane >> 3;                       // 0..7 row-within-instr (also swizzle key)
    int sw8 = ((lane & 7) ^ srow) << 3;         // swizzled global chunk offset (u16 elems)
    const u16* pA = W2r + (size_t)o0 * KTOT;
    const u16* pSb = S + (((size_t)(bl * 9)) << 12) * CCH;

    f32x4 acc[4][4];
    f32x4 z = {0.f, 0.f, 0.f, 0.f};
#pragma unroll
    for (int i = 0; i < 4; ++i)
#pragma unroll
        for (int j = 0; j < 4; ++j) acc[i][j] = z;

    auto stage = [&](int s, int d) {
        int k9 = s >> 2, cs = s & 3;
        int koffA = k9 * 256 + cs * 64;
        const u16* pB = pSb + ((size_t)k9 << 12) * CCH + cs * 64;
#pragma unroll
        for (int i = 0; i < 4; ++i) {
            int inst = wv * 4 + i;
            int row = inst * 8 + srow;
            ldg_lds16(pA + (size_t)row * KTOT + koffA + sw8, &AS[d][inst * 512]);
            ldg_lds16(pB + (size_t)(pos0 + row) * CCH + sw8, &BS[d][inst * 512]);
        }
    };

    stage(0, 0);
    __syncthreads();

    int buf = 0;
    int m = lane & 15, q = lane >> 4, key = lane & 7;
    for (int step = 0; step < 36; ++step) {
        if (step < 35) stage(step + 1, buf ^ 1);
#pragma unroll
        for (int j = 0; j < 2; ++j) {
            int slot8 = (((j * 4 + q) ^ key) << 3);
            short8 af[4], bfr[4];
#pragma unroll
            for (int ao = 0; ao < 4; ++ao)
                af[ao] = *(const short8*)&AS[buf][(wr * 64 + ao * 16 + m) * 64 + slot8];
#pragma unroll
            for (int bn = 0; bn < 4; ++bn)
                bfr[bn] = *(const short8*)&BS[buf][(wc * 64 + bn * 16 + m) * 64 + slot8];
#pragma unroll
            for (int ao = 0; ao < 4; ++ao)
#pragma unroll
                for (int bn = 0; bn < 4; ++bn)
                    acc[ao][bn] = __builtin_amdgcn_mfma_f32_16x16x32_bf16(af[ao], bfr[bn], acc[ao][bn], 0, 0, 0);
        }
        __syncthreads();
        buf ^= 1;
    }

    // epilogue: bias + sigmoid -> fp32 NCHW
    int nn = lane & 15;
#pragma unroll
    for (int ao = 0; ao < 4; ++ao) {
        int ob = o0 + wr * 64 + ao * 16 + q * 4;
#pragma unroll
        for (int bn = 0; bn < 4; ++bn) {
            int pos = pos0 + wc * 64 + bn * 16 + nn;
#pragma unroll
            for (int r = 0; r < 4; ++r) {
                float v = acc[ao][bn][r] + bias[ob + r];
                float sg = 1.0f / (1.0f + __expf(-v));
                out[(size_t)((b * CCH + ob + r) * NPOS) + pos] = sg;
            }
        }
    }
}

extern "C" void kernel_launch(void* const* d_in, const int* in_sizes, int n_in,
                              void* d_out, int out_size, void* d_ws, size_t ws_size,
                              hipStream_t stream) {
    const float* x     = (const float*)d_in[0];
    const float* w_off = (const float*)d_in[1];
    const float* b_off = (const float*)d_in[2];
    const float* w     = (const float*)d_in[3];
    const float* bias  = (const float*)d_in[4];
    float* out = (float*)d_out;

    char* ws = (char*)d_ws;
    u16*    xT    = (u16*)ws;
    u16*    W2r   = (u16*)(ws + W2R_OFF);
    u16*    Woff2 = (u16*)(ws + WOFF2_OFF);
    float*  P     = (float*)(ws + P_OFF);
    float2* off2  = (float2*)(ws + OFF2_OFF);
    u16*    S     = (u16*)(ws + S_OFF);

    // batches per S-pass, adaptive to ws size
    int nb = 8;
    while (nb > 1 && ws_size < S_OFF + (size_t)nb * S_BATCH) nb >>= 1;
    if (ws_size < S_OFF + S_BATCH) return;

    k_pre<<<2825, 256, 0, stream>>>(w, w_off, x, W2r, Woff2, xT);
    k_offconv<<<dim3(8, 9, 32), 256, 0, stream>>>(xT, Woff2, P);
    k_reduce<<<dim3(8, 16), 256, 0, stream>>>(P, b_off, off2);
    for (int p = 0; p < 8; p += nb) {
        k_sample<<<dim3(nb, 9, 64), 256, 0, stream>>>(xT, off2, S, p);
        k_gemm<<<dim3(nb, 2, 32), 256, 0, stream>>>(S, W2r, bias, out, p);
    }
}